// Round 1
// baseline (32.402 us; speedup 1.0000x reference)
//
#include <hip/hip_runtime.h>

// Problem constants (match reference)
constexpr int Bv = 4;
constexpr int Cv = 1024;
constexpr int Hv = 64;
constexpr int Wv = 64;
constexpr int NROIS = 256;
constexpr int HWv = Hv * Wv;          // 4096
constexpr int PIX = Bv * HWv;         // 16384
constexpr int G = 16;                 // channel groups for k1
constexpr int CPG = Cv / G;           // 64 channels per group

// ---------------------------------------------------------------------------
// k1: partial channel-summed squared diff. Each thread owns 4 consecutive
// pixels (float4) and one channel group; plain stores to partial[g][pix].
// grid: (G * PIX/4) / 256 = 256 blocks x 256 threads.
// ---------------------------------------------------------------------------
__global__ __launch_bounds__(256) void k_diff2_partial(
    const float* __restrict__ std_f, const float* __restrict__ tch_f,
    float* __restrict__ partial) {
  int t = blockIdx.x * blockDim.x + threadIdx.x;  // [0, 65536)
  int g = t >> 12;           // channel group [0,16)
  int v = t & 4095;          // float4-unit index over all pixels
  int p = v << 2;            // pixel index [0, 16384), 4 consecutive
  int b = p >> 12;           // batch  (HW = 4096)
  int hw = p & 4095;         // pixel within batch

  const float* ps = std_f + ((size_t)b * Cv + (size_t)g * CPG) * HWv + hw;
  const float* pt = tch_f + ((size_t)b * Cv + (size_t)g * CPG) * HWv + hw;

  float4 acc = make_float4(0.f, 0.f, 0.f, 0.f);
#pragma unroll 4
  for (int c = 0; c < CPG; ++c) {
    float4 s = *reinterpret_cast<const float4*>(ps + (size_t)c * HWv);
    float4 q = *reinterpret_cast<const float4*>(pt + (size_t)c * HWv);
    float dx = s.x - q.x, dy = s.y - q.y, dz = s.z - q.z, dw = s.w - q.w;
    acc.x += dx * dx;
    acc.y += dy * dy;
    acc.z += dz * dz;
    acc.w += dw * dw;
  }
  *reinterpret_cast<float4*>(partial + (size_t)g * PIX + p) = acc;
}

// ---------------------------------------------------------------------------
// k1b: reduce G partials -> diff2[pix]. 64 blocks x 256 threads.
// ---------------------------------------------------------------------------
__global__ __launch_bounds__(256) void k_diff2_reduce(
    const float* __restrict__ partial, float* __restrict__ diff2) {
  int p = blockIdx.x * blockDim.x + threadIdx.x;  // [0, 16384)
  float acc = 0.f;
#pragma unroll
  for (int g = 0; g < G; ++g) acc += partial[(size_t)g * PIX + p];
  diff2[p] = acc;
}

// ---------------------------------------------------------------------------
// block reduction helper (256 threads, wave64)
// ---------------------------------------------------------------------------
__device__ __forceinline__ float block_reduce_256(float v) {
  for (int off = 32; off > 0; off >>= 1) v += __shfl_down(v, off, 64);
  __shared__ float smem[4];
  int lane = threadIdx.x & 63;
  int wid = threadIdx.x >> 6;
  if (lane == 0) smem[wid] = v;
  __syncthreads();
  float r = 0.f;
  if (threadIdx.x == 0) r = smem[0] + smem[1] + smem[2] + smem[3];
  return r;
}

// ---------------------------------------------------------------------------
// k2: one block per ROI; rectangle sum over diff2 -> roi_mse (0 if invalid).
// grid: B*NROIS = 1024 blocks x 256 threads.
// ---------------------------------------------------------------------------
__global__ __launch_bounds__(256) void k_roi_mse(
    const float* __restrict__ diff2, const float* __restrict__ rois,
    const int* __restrict__ stride_p, float* __restrict__ roi_out) {
  int roi_id = blockIdx.x;          // [0, 1024)
  int b = roi_id >> 8;              // / NROIS
  const float* r = rois + (size_t)roi_id * 5;
  float inv_stride = 1.0f / (float)stride_p[0];

  int x1 = (int)floorf(r[1] * inv_stride);
  int y1 = (int)floorf(r[2] * inv_stride);
  int x2 = (int)floorf(r[3] * inv_stride);
  int y2 = (int)floorf(r[4] * inv_stride);

  bool valid = (y2 > y1) && (x2 > x1);
  if (!valid) {
    if (threadIdx.x == 0) roi_out[roi_id] = 0.f;
    return;
  }

  int wroi = x2 - x1 + 1;
  int hroi = y2 - y1 + 1;
  int area = wroi * hroi;

  const float* d2 = diff2 + (size_t)b * HWv;
  float acc = 0.f;
  for (int idx = threadIdx.x; idx < area; idx += 256) {
    int yy = y1 + idx / wroi;
    int xx = x1 + idx % wroi;
    acc += d2[yy * Wv + xx];
  }
  float sse = block_reduce_256(acc);
  if (threadIdx.x == 0) {
    roi_out[roi_id] = sse / ((float)Cv * (float)area);
  }
}

// ---------------------------------------------------------------------------
// k3: final sum over B*NROIS roi_mse values -> d_out[0]. 1 block x 256.
// ---------------------------------------------------------------------------
__global__ __launch_bounds__(256) void k_final(
    const float* __restrict__ roi_out, float* __restrict__ out) {
  float acc = 0.f;
#pragma unroll
  for (int i = 0; i < (Bv * NROIS) / 256; ++i)
    acc += roi_out[i * 256 + threadIdx.x];
  float total = block_reduce_256(acc);
  if (threadIdx.x == 0) out[0] = total / (float)(Bv * NROIS);
}

extern "C" void kernel_launch(void* const* d_in, const int* in_sizes, int n_in,
                              void* d_out, int out_size, void* d_ws,
                              size_t ws_size, hipStream_t stream) {
  const float* std_f = (const float*)d_in[0];
  const float* tch_f = (const float*)d_in[1];
  const float* rois = (const float*)d_in[2];
  const int* stride_p = (const int*)d_in[3];
  float* out = (float*)d_out;

  // workspace layout: partial [G*PIX] | diff2 [PIX] | roi_out [B*NROIS]
  float* partial = (float*)d_ws;
  float* diff2 = partial + (size_t)G * PIX;
  float* roi_out = diff2 + PIX;

  k_diff2_partial<<<(G * PIX / 4) / 256, 256, 0, stream>>>(std_f, tch_f,
                                                           partial);
  k_diff2_reduce<<<PIX / 256, 256, 0, stream>>>(partial, diff2);
  k_roi_mse<<<Bv * NROIS, 256, 0, stream>>>(diff2, rois, stride_p, roi_out);
  k_final<<<1, 256, 0, stream>>>(roi_out, out);
}